// Round 1
// 964.931 us; speedup vs baseline: 1.0189x; 1.0189x over previous
//
#include <hip/hip_runtime.h>
#include <math.h>

#define TT 150
#define BB 64
#define DD 2000
#define SS 3000
#define EE 100000
#define EEPAD 124160   // >= EE + SS*7 (arcs padded per-state to multiple of 8)
#define RESC 16
#define NSLOT 9
#define RESCC 0x1p-46f // exact pow2 rescale every 16 steps (growth ~7.42^16 ~= 2^46.3)

#define NT 1024        // threads per block (16 waves)
#define NBLK 256       // 1 block per CU
#define NG 32          // groups, 2 batch lanes each
#define GB 8           // blocks per group (same XCD iff bid%8 maps to XCD)
#define CAP 14080      // LDS arc slots per block (max slice ~13.9k)
#define ASTRD 3072     // dwords per alpha buffer per group (SS=3000 padded)
#define NSTMAX 1536
#define FLGSTR 32      // dwords between flags (128 B)
#define NEXB 32

// dynamic LDS layout (bytes)
#define OFF_ARC    0                 // CAP*8        = 112640
#define OFF_ALPHA  112640            // SS*8  -> 24064   (float2 per state)
#define OFF_EX     136704            // DD*8  -> 16128   (float2 per pdf)
#define OFF_RBP    152832            // (NSTMAX+1)*4 -> 6160
#define OFF_RED    158992            // 256*4 = 1024
#define OFF_SH     160016            // 16
#define DYNLDS     160032

// idx = (from<<3) | (pdf<<19): both halves are ready-made BYTE offsets into
// the float2 LDS tables (from*8 <= 23992 fits 15 bits; pdf*8 <= 15992 fits 16).
struct __align__(8) ArcT2 { unsigned idx; float ew; };

__device__ inline float b2f(unsigned short u) {
    union { unsigned u32; float f; } x; x.u32 = ((unsigned)u) << 16; return x.f;
}
__device__ inline unsigned short f2b(float f) {
    union { float f; unsigned u; } x; x.f = f;
    unsigned r = x.u + 0x7FFF + ((x.u >> 16) & 1);       // RNE, positive finite only
    return (unsigned short)(r >> 16);
}
__device__ inline float u2f(unsigned u) {
    union { unsigned u32; float f; } x; x.u32 = u; return x.f;
}

// ---------------- setup kernels ----------------
__global__ void k_init0(int* __restrict__ counts, unsigned* __restrict__ flags,
                        float* __restrict__ partial)
{
    int i = blockIdx.x * blockDim.x + threadIdx.x;
    if (i < SS) counts[i] = 0;
    if (i < 2 * NBLK * FLGSTR) flags[i] = 0u;
    if (i < NG * 2) partial[i] = 0.f;
}

__global__ void k_zeroarcs(ArcT2* __restrict__ arcs)
{
    int i = blockIdx.x * blockDim.x + threadIdx.x;
    if (i < EEPAD) { ArcT2 z; z.idx = 0; z.ew = 0.f; arcs[i] = z; }
}

__global__ void k_hist(const int* __restrict__ to_state, int* __restrict__ counts)
{
    int e = blockIdx.x * blockDim.x + threadIdx.x;
    if (e < EE) atomicAdd(&counts[to_state[e]], 1);
}

// prefix over counts padded to multiple of 8
__global__ void k_scan(const int* __restrict__ counts, int* __restrict__ rp,
                       int* __restrict__ cur)
{
    __shared__ int ls[1024];
    int tid = threadIdx.x;
    int s0 = tid * 3;
    int a0 = (s0 + 0 < SS) ? ((counts[s0 + 0] + 7) & ~7) : 0;
    int a1 = (s0 + 1 < SS) ? ((counts[s0 + 1] + 7) & ~7) : 0;
    int a2 = (s0 + 2 < SS) ? ((counts[s0 + 2] + 7) & ~7) : 0;
    int tsum = a0 + a1 + a2;
    ls[tid] = tsum;
    __syncthreads();
    for (int off = 1; off < 1024; off <<= 1) {
        int v = ls[tid];
        int add = (tid >= off) ? ls[tid - off] : 0;
        __syncthreads();
        ls[tid] = v + add;
        __syncthreads();
    }
    int excl = ls[tid] - tsum;
    if (s0 + 0 < SS) { rp[s0 + 0] = excl; cur[s0 + 0] = excl; }
    excl += a0;
    if (s0 + 1 < SS) { rp[s0 + 1] = excl; cur[s0 + 1] = excl; }
    excl += a1;
    if (s0 + 2 < SS) { rp[s0 + 2] = excl; cur[s0 + 2] = excl; }
    if (tid == 1023) rp[SS] = ls[1023];
}

// arc-balanced split into GB slices
__global__ void k_split(const int* __restrict__ rp, int* __restrict__ split)
{
    int j = threadIdx.x;
    if (j > GB) return;
    if (j == 0)  { split[0] = 0; return; }
    if (j == GB) { split[GB] = SS; return; }
    long long total = rp[SS];
    int target = (int)((total * j) / GB);
    int lo = 0, hi = SS;
    while (lo < hi) { int mid = (lo + hi) >> 1; if (rp[mid] >= target) hi = mid; else lo = mid + 1; }
    split[j] = lo;
}

__global__ void k_scatter(const int* __restrict__ from_state, const int* __restrict__ to_state,
                          const int* __restrict__ pdf_id, const float* __restrict__ trans_logw,
                          int* __restrict__ cur, ArcT2* __restrict__ arcs)
{
    int e = blockIdx.x * blockDim.x + threadIdx.x;
    if (e >= EE) return;
    int s = to_state[e];
    int pos = atomicAdd(&cur[s], 1);
    ArcT2 a;
    a.idx = ((unsigned)from_state[e] << 3) | ((unsigned)pdf_id[e] << 19);
    a.ew = __expf(trans_logw[e]);
    arcs[pos] = a;
}

// ---------------- cooperative mega-kernel, verified XCD-local exchange ----------------
__global__ void __launch_bounds__(NT, 4) k_coop(
    const ArcT2* __restrict__ arcs, const int* __restrict__ rp,
    const int* __restrict__ split,
    const float* __restrict__ input, const float* __restrict__ init_logp,
    const float* __restrict__ final_logp,
    float* __restrict__ partial,         // [NG][2]
    unsigned* __restrict__ A_all,        // [NG][2][ASTRD] packed 2xbf16
    unsigned* __restrict__ flags,        // [2][NBLK][FLGSTR]
    unsigned* __restrict__ xcdbuf,       // [NBLK]
    float* __restrict__ out)
{
    extern __shared__ char dsm[];
    ArcT2*    larc  = (ArcT2*)(dsm + OFF_ARC);
    float2*   laf   = (float2*)(dsm + OFF_ALPHA);   // f32 pair per state
    float2*   lef   = (float2*)(dsm + OFF_EX);      // f32 pair per pdf
    int*      rbp   = (int*)(dsm + OFF_RBP);
    float*    redf  = (float*)(dsm + OFF_RED);
    int*      sh    = (int*)(dsm + OFF_SH);

    int tid = threadIdx.x, bid = blockIdx.x;
    int x = bid & 7, y = (bid >> 3) & 3, j = bid >> 5;   // presumed-XCD, grp-in-XCD, member
    int g = x * 4 + y;                                   // group 0..31
    int lane = tid & 63, wave = tid >> 6;
    int oct = lane >> 3, sub = lane & 7;

    unsigned* Ag       = A_all + (size_t)g * (2 * ASTRD);
    unsigned* stepf    = flags;
    unsigned* auxf     = flags + (size_t)NBLK * FLGSTR;
    unsigned* myflag   = stepf + (size_t)(g * GB + j) * FLGSTR;
    unsigned* grpflag  = stepf + (size_t)(g * GB) * FLGSTR;
    unsigned* myflag2  = auxf + (size_t)(g * GB + j) * FLGSTR;
    unsigned* grpflag2 = auxf + (size_t)(g * GB) * FLGSTR;
    const float* inpG  = input + (size_t)(2 * g) * DD;

    int s0 = split[j], s1 = split[j + 1];
    int nst = s1 - s0;
    if (nst > NSTMAX) nst = NSTMAX;                      // safety (never expected)

    // ---- stage rp slice + arcs to LDS ----
    for (int i = tid; i <= nst; i += NT) rbp[i] = rp[s0 + i];
    __syncthreads();
    int rb0 = rbp[0];
    {
        int staged = rbp[nst] - rb0; if (staged > CAP) staged = CAP;
        for (int i = tid; i < staged; i += NT) larc[i] = arcs[rb0 + i];
    }

    // ---- publish XCC_ID (s_getreg id=20, offset=0, width=4 -> imm 6164) ----
    unsigned xcd = __builtin_amdgcn_s_getreg(6164) & 0xF;
    if (tid == 0)
        __hip_atomic_store(&xcdbuf[g * GB + j], xcd, __ATOMIC_RELAXED, __HIP_MEMORY_SCOPE_AGENT);
    __syncthreads();
    if (tid == 0)
        __hip_atomic_store(myflag2, 1u, __ATOMIC_RELAXED, __HIP_MEMORY_SCOPE_AGENT);
    // global aux barrier: wave0 polls all 256 aux flags (4 per lane)
    if (wave == 0) {
        while (true) {
            unsigned ok = 1;
            #pragma unroll
            for (int r = 0; r < 4; ++r) {
                unsigned v = __hip_atomic_load(auxf + (size_t)(lane * 4 + r) * FLGSTR,
                                               __ATOMIC_RELAXED, __HIP_MEMORY_SCOPE_AGENT);
                ok &= (v >= 1u);
            }
            if (__ballot(ok != 0) == ~0ULL) break;
            __builtin_amdgcn_s_sleep(1);
        }
    }
    __syncthreads();
    // decide protocol: fast iff my group is on ONE XCD and getreg is plausible
    {
        int* xint = (int*)redf;
        if (tid < NBLK)
            xint[tid] = (int)__hip_atomic_load(&xcdbuf[tid], __ATOMIC_RELAXED,
                                               __HIP_MEMORY_SCOPE_AGENT);
        __syncthreads();
        if (tid == 0) {
            int x0 = xint[g * GB];
            int uni = 1;
            for (int m = 1; m < GB; ++m) uni &= (xint[g * GB + m] == x0);
            int first = xint[0], distinct = 0;
            for (int i = 1; i < NBLK; ++i) distinct |= (xint[i] != first);
            sh[0] = uni && distinct;
        }
        __syncthreads();
    }
    const bool fast = (sh[0] != 0);
    __syncthreads();

    // ---- alpha0 (own slice) with protocol-matched stores ----
    for (int i = tid; i < nst; i += NT) {
        int s = s0 + i;
        unsigned short h = f2b(__expf(init_logp[s]));
        unsigned pk = (unsigned)h | ((unsigned)h << 16);
        if (fast) Ag[s] = pk;                            // plain store -> shared L2
        else __hip_atomic_store(Ag + s, pk, __ATOMIC_RELAXED, __HIP_MEMORY_SCOPE_AGENT);
    }
    __syncthreads();                                     // stores drained
    unsigned ep = 1;
    if (tid == 0) {
        if (fast) *(volatile unsigned*)myflag = ep;
        else __hip_atomic_store(myflag, ep, __ATOMIC_RELAXED, __HIP_MEMORY_SCOPE_AGENT);
    }
    {   // ex frame 0, full f32 (overlaps other blocks' arrival)
        for (int r = 0; r < 2; ++r) {
            int d = r * NT + tid;
            if (d < DD)
                lef[d] = make_float2(__expf(inpG[d]), __expf(inpG[DD + d]));
        }
    }
    if (wave == 0) {
        while (true) {
            unsigned v = ep;
            if (lane < GB) {
                v = fast ? *(volatile const unsigned*)(grpflag + lane * FLGSTR)
                         : __hip_atomic_load(grpflag + lane * FLGSTR, __ATOMIC_RELAXED,
                                             __HIP_MEMORY_SCOPE_AGENT);
            }
            if (__ballot(v >= ep) == ~0ULL) break;
            __builtin_amdgcn_s_sleep(1);
        }
    }
    __syncthreads();

    float vf0 = 0.f, vf1 = 0.f;
    const char* lafc = (const char*)laf;
    const char* lefc = (const char*)lef;

    // ---- 150 steps ----
    for (int k = 0; k < TT; ++k) {
        const unsigned* Ap32 = Ag + (k & 1) * ASTRD;
        unsigned*       An32 = Ag + ((k + 1) & 1) * ASTRD;
        bool last = (k == TT - 1);
        bool resc = (((k + 1) & (RESC - 1)) == 0);

        // phase A: alpha_k (12 KB packed bf16) -> LDS, unpacked once to f32 pairs
        if (fast) {
            for (int idx = tid; idx < SS; idx += NT) {
                unsigned v = *(volatile const unsigned*)(Ap32 + idx);   // L1-bypass
                laf[idx] = make_float2(u2f(v << 16), u2f(v & 0xFFFF0000u));
            }
        } else {
            for (int idx = tid; idx < SS / 2; idx += NT) {
                unsigned long long v = __hip_atomic_load(
                    (const unsigned long long*)Ap32 + idx, __ATOMIC_RELAXED,
                    __HIP_MEMORY_SCOPE_AGENT);
                unsigned lo = (unsigned)v, hi = (unsigned)(v >> 32);
                laf[idx * 2 + 0] = make_float2(u2f(lo << 16), u2f(lo & 0xFFFF0000u));
                laf[idx * 2 + 1] = make_float2(u2f(hi << 16), u2f(hi & 0xFFFF0000u));
            }
        }
        __syncthreads();

        // phase B: gather own states (8 lanes per state, 8 states per wave)
        for (int base = wave * 8; base < nst; base += 128) {
            int li = base + oct;
            bool has = (li < nst);
            float acc0 = 0.f, acc1 = 0.f;
            int sg = 0;
            if (has) {
                sg = s0 + li;
                int ra = rbp[li], re = rbp[li + 1];
                int nit = (re - ra) >> 3;
                if (re - rb0 <= CAP) {
                    int bix = ra - rb0 + sub;
                    for (int t = 0; t < nit; ++t) {
                        ArcT2 a = larc[bix + t * 8];
                        float2 al = *(const float2*)(lafc + (a.idx & 0xFFFFu));
                        float2 ev = *(const float2*)(lefc + (a.idx >> 16));
                        acc0 = fmaf(al.x, a.ew * ev.x, acc0);
                        acc1 = fmaf(al.y, a.ew * ev.y, acc1);
                    }
                } else {
                    for (int t = 0; t < nit; ++t) {      // safety overflow path
                        ArcT2 a = arcs[ra + t * 8 + sub];
                        float2 al = *(const float2*)(lafc + (a.idx & 0xFFFFu));
                        float2 ev = *(const float2*)(lefc + (a.idx >> 16));
                        acc0 = fmaf(al.x, a.ew * ev.x, acc0);
                        acc1 = fmaf(al.y, a.ew * ev.y, acc1);
                    }
                }
            }
            acc0 += __shfl_xor(acc0, 1, 64); acc1 += __shfl_xor(acc1, 1, 64);
            acc0 += __shfl_xor(acc0, 2, 64); acc1 += __shfl_xor(acc1, 2, 64);
            acc0 += __shfl_xor(acc0, 4, 64); acc1 += __shfl_xor(acc1, 4, 64);
            if (has && sub == 0) {
                if (resc) { acc0 *= RESCC; acc1 *= RESCC; }
                if (last) {
                    float ef = __expf(final_logp[sg]);
                    vf0 = fmaf(acc0, ef, vf0);
                    vf1 = fmaf(acc1, ef, vf1);
                } else {
                    unsigned pk = (unsigned)f2b(acc0) | ((unsigned)f2b(acc1) << 16);
                    if (fast) An32[sg] = pk;             // plain store -> shared L2
                    else __hip_atomic_store(An32 + sg, pk, __ATOMIC_RELAXED,
                                            __HIP_MEMORY_SCOPE_AGENT);
                }
            }
        }
        if (last) break;
        __syncthreads();                                 // stores drained (vmcnt 0)
        ++ep;
        if (tid == 0) {
            if (fast) *(volatile unsigned*)myflag = ep;
            else __hip_atomic_store(myflag, ep, __ATOMIC_RELAXED, __HIP_MEMORY_SCOPE_AGENT);
        }
        {   // ex_{k+1} (independent of alpha) — overlaps others' arrival
            const float* fr = inpG + (size_t)(k + 1) * BB * DD;
            for (int r = 0; r < 2; ++r) {
                int d = r * NT + tid;
                if (d < DD)
                    lef[d] = make_float2(__expf(fr[d]), __expf(fr[DD + d]));
            }
        }
        if (wave == 0) {
            while (true) {
                unsigned v = ep;
                if (lane < GB) {
                    v = fast ? *(volatile const unsigned*)(grpflag + lane * FLGSTR)
                             : __hip_atomic_load(grpflag + lane * FLGSTR, __ATOMIC_RELAXED,
                                                 __HIP_MEMORY_SCOPE_AGENT);
                }
                if (__ballot(v >= ep) == ~0ULL) break;
                __builtin_amdgcn_s_sleep(1);
            }
        }
        __syncthreads();
    }

    // ---- epilogue: reduce objf over this block's states ----
    if (sub == 0) {
        redf[(wave * 8 + oct) * 2 + 0] = vf0;
        redf[(wave * 8 + oct) * 2 + 1] = vf1;
    }
    __syncthreads();
    if (tid < 2) {
        float S = 0.f;
        for (int i = 0; i < 128; ++i) S += redf[i * 2 + tid];
        __hip_atomic_fetch_add(&partial[g * 2 + tid], S, __ATOMIC_RELAXED,
                               __HIP_MEMORY_SCOPE_AGENT);
    }
    __syncthreads();
    if (tid == 0)
        __hip_atomic_store(myflag2, 2u, __ATOMIC_RELAXED, __HIP_MEMORY_SCOPE_AGENT);
    if (j == 0) {
        if (wave == 0) {
            while (true) {
                unsigned v = 2;
                if (lane < GB)
                    v = __hip_atomic_load(grpflag2 + lane * FLGSTR, __ATOMIC_RELAXED,
                                          __HIP_MEMORY_SCOPE_AGENT);
                if (__ballot(v >= 2) == ~0ULL) break;
                __builtin_amdgcn_s_sleep(1);
            }
        }
        __syncthreads();
        if (tid < 2) {
            float S = __hip_atomic_load(&partial[g * 2 + tid], __ATOMIC_RELAXED,
                                        __HIP_MEMORY_SCOPE_AGENT);
            float lg = logf(S) + (float)(NSLOT * 46) * 0.69314718055994531f;
            atomicAdd(out, lg);
        }
    }
}

// ---------------- fallback path (round-6 per-step kernels) ----------------
template <int THREADS>
__device__ inline void transpose_exp_t(const float* __restrict__ frame,
                                       unsigned short* __restrict__ dst,
                                       int tile_id, int tid, unsigned short* smem)
{
    int d0 = tile_id * 64;
    #pragma unroll
    for (int it = 0; it < 4096 / THREADS; ++it) {
        int idx = it * THREADS + tid;
        int dl = idx & 63, bl = idx >> 6;
        int d = d0 + dl;
        float v = 0.f;
        if (d < DD) v = __expf(frame[bl * DD + d]);
        smem[dl * 65 + bl] = f2b(v);
    }
    __syncthreads();
    #pragma unroll
    for (int it = 0; it < 4096 / THREADS; ++it) {
        int idx = it * THREADS + tid;
        int bo = idx & 63, dq = idx >> 6;
        int d = d0 + dq;
        if (d < DD) dst[(d << 6) + bo] = smem[dq * 65 + bo];
    }
    __syncthreads();
}

__global__ void k_initA(const float* __restrict__ init_logp,
                        unsigned short* __restrict__ A0, float* __restrict__ M2)
{
    int idx = blockIdx.x * blockDim.x + threadIdx.x;
    if (idx < SS * BB) A0[idx] = f2b(__expf(init_logp[idx >> 6]));
    if (idx < NSLOT * 16 * 64) M2[idx] = 0.f;
}

__global__ void k_transpose0(const float* __restrict__ frame, unsigned short* __restrict__ dst)
{
    __shared__ unsigned short tile[64 * 65];
    transpose_exp_t<256>(frame, dst, blockIdx.x, threadIdx.x, tile);
}

__global__ void __launch_bounds__(256) k_step(
    const ArcT2* __restrict__ arcs, const int* __restrict__ rp,
    const unsigned short* __restrict__ Ap, unsigned short* __restrict__ An,
    const unsigned short* __restrict__ ec,
    const float* __restrict__ frameNext, unsigned short* __restrict__ en,
    float* __restrict__ M2, int maxSlot, int useSlot)
{
    __shared__ unsigned short tile[64 * 65];
    __shared__ float part[256];
    __shared__ float rcpA[64];
    int tid = threadIdx.x, bid = blockIdx.x;
    if (bid >= SS) { transpose_exp_t<256>(frameNext, en, bid - SS, tid, tile); return; }
    int lane = tid & 63, wave = tid >> 6;
    if (useSlot >= 0 && wave == 0) {
        const float* Mrow = M2 + useSlot * (16 * 64);
        float m = Mrow[lane];
        #pragma unroll
        for (int g = 1; g < 16; ++g) m = fmaxf(m, Mrow[g * 64 + lane]);
        rcpA[lane] = 1.0f / m;
    }
    int rbeg = rp[bid], rend = rp[bid + 1];
    float acc = 0.f;
    for (int i = rbeg + wave; i < rend; i += 4) {
        ArcT2 a = arcs[i];
        int from = (a.idx & 0xFFFF) >> 3, pdf = a.idx >> 19;
        acc = fmaf(b2f(Ap[(from << 6) + lane]), a.ew * b2f(ec[(pdf << 6) + lane]), acc);
    }
    part[tid] = acc;
    __syncthreads();
    if (wave == 0) {
        float sum = part[lane] + part[64 + lane] + part[128 + lane] + part[192 + lane];
        if (useSlot >= 0) sum *= rcpA[lane];
        An[(bid << 6) + lane] = f2b(sum);
        if (maxSlot >= 0)
            atomicMax((unsigned*)&M2[maxSlot * (16 * 64) + (bid & 15) * 64 + lane],
                      __float_as_uint(sum));
    }
}

__global__ void k_fin(const unsigned short* __restrict__ AT, const float* __restrict__ final_logp,
                      const float* __restrict__ M2, float* __restrict__ out)
{
    __shared__ float red[1024];
    int tid = threadIdx.x;
    int lane = tid & 63, chunk = tid >> 6;
    float psum = 0.f;
    for (int s = chunk; s < SS; s += 16)
        psum += b2f(AT[(s << 6) + lane]) * __expf(final_logp[s]);
    red[tid] = psum;
    __syncthreads();
    if (tid < 64) {
        float sum = 0.f;
        #pragma unroll
        for (int c = 0; c < 16; ++c) sum += red[c * 64 + tid];
        float lg = logf(sum);
        #pragma unroll
        for (int r = 0; r < NSLOT; ++r) {
            const float* Mrow = M2 + r * (16 * 64);
            float m = Mrow[tid];
            #pragma unroll
            for (int g = 1; g < 16; ++g) m = fmaxf(m, Mrow[g * 64 + tid]);
            lg += logf(m);
        }
        #pragma unroll
        for (int off = 32; off > 0; off >>= 1) lg += __shfl_down(lg, off);
        if (tid == 0) out[0] = lg;
    }
}

extern "C" void kernel_launch(void* const* d_in, const int* in_sizes, int n_in,
                              void* d_out, int out_size, void* d_ws, size_t ws_size,
                              hipStream_t stream)
{
    const float* input      = (const float*)d_in[0];
    const float* trans_logw = (const float*)d_in[1];
    const float* init_logp  = (const float*)d_in[2];
    const float* final_logp = (const float*)d_in[3];
    const int*   from_state = (const int*)d_in[4];
    const int*   to_state   = (const int*)d_in[5];
    const int*   pdf_id     = (const int*)d_in[6];
    float* out = (float*)d_out;

    char* ws = (char*)d_ws;
    size_t off = 0;
    auto alloc = [&](size_t bytes) -> char* {
        char* p = ws + off;
        off = (off + bytes + 255) & ~(size_t)255;
        return p;
    };
    ArcT2* arcs  = (ArcT2*)alloc((size_t)EEPAD * sizeof(ArcT2));
    int* rp      = (int*)alloc((size_t)(SS + 1) * 4);
    int* cur     = (int*)alloc((size_t)SS * 4);
    int* counts  = (int*)alloc((size_t)SS * 4);
    int* split   = (int*)alloc((size_t)(GB + 1) * 4);
    unsigned* A_all = (unsigned*)alloc((size_t)NG * 2 * ASTRD * 4);
    float* partial  = (float*)alloc((size_t)NG * 2 * 4);
    unsigned* flags = (unsigned*)alloc((size_t)2 * NBLK * FLGSTR * 4);
    unsigned* xcdbuf = (unsigned*)alloc((size_t)NBLK * 4);
    // fallback buffers
    unsigned short* A0  = (unsigned short*)alloc((size_t)SS * BB * 2);
    unsigned short* A1  = (unsigned short*)alloc((size_t)SS * BB * 2);
    unsigned short* EX0 = (unsigned short*)alloc((size_t)DD * BB * 2);
    unsigned short* EX1 = (unsigned short*)alloc((size_t)DD * BB * 2);
    float* M2    = (float*)alloc((size_t)NSLOT * 16 * 64 * 4);
    (void)ws_size; (void)in_sizes; (void)n_in; (void)out_size;

    k_init0<<<64, 256, 0, stream>>>(counts, flags, partial);
    k_zeroarcs<<<(EEPAD + 255) / 256, 256, 0, stream>>>(arcs);
    k_hist<<<(EE + 255) / 256, 256, 0, stream>>>(to_state, counts);
    k_scan<<<1, 1024, 0, stream>>>(counts, rp, cur);
    k_split<<<1, 16, 0, stream>>>(rp, split);
    k_scatter<<<(EE + 255) / 256, 256, 0, stream>>>(from_state, to_state, pdf_id,
                                                    trans_logw, cur, arcs);
    hipMemsetAsync(d_out, 0, sizeof(float), stream);

    hipFuncSetAttribute((const void*)k_coop, hipFuncAttributeMaxDynamicSharedMemorySize,
                        DYNLDS);
    int nb = 0;
    hipOccupancyMaxActiveBlocksPerMultiprocessor(&nb, (const void*)k_coop, NT, DYNLDS);
    if (nb >= 1) {
        void* kp[11] = {
            (void*)&arcs, (void*)&rp, (void*)&split, (void*)&input, (void*)&init_logp,
            (void*)&final_logp, (void*)&partial, (void*)&A_all, (void*)&flags,
            (void*)&xcdbuf, (void*)&out
        };
        hipError_t e = hipLaunchCooperativeKernel((const void*)k_coop, dim3(NBLK), dim3(NT),
                                                  kp, DYNLDS, stream);
        if (e == hipSuccess) return;
    }

    // Fallback: per-step kernels (bf16 state), known-passing structure.
    k_initA<<<(SS * BB + 255) / 256, 256, 0, stream>>>(init_logp, A0, M2);
    k_transpose0<<<NEXB, 256, 0, stream>>>(input, EX0);
    unsigned short* A[2]  = {A0, A1};
    unsigned short* EX[2] = {EX0, EX1};
    for (int k = 0; k < TT; ++k) {
        int kn = k + 1;
        int useSlot = (k > 0 && (k % RESC) == 0) ? (k / RESC - 1) : -1;
        int maxSlot = (kn < TT && (kn % RESC) == 0) ? (kn / RESC - 1) : -1;
        int grid = SS + ((kn < TT) ? NEXB : 0);
        const float* fnext = (kn < TT) ? (input + (size_t)kn * BB * DD) : nullptr;
        k_step<<<grid, 256, 0, stream>>>(arcs, rp, A[k & 1], A[kn & 1], EX[k & 1],
                                         fnext, EX[kn & 1], M2, maxSlot, useSlot);
    }
    k_fin<<<1, 1024, 0, stream>>>(A[TT & 1], final_logp, M2, out);
}

// Round 2
// 940.752 us; speedup vs baseline: 1.0451x; 1.0257x over previous
//
#include <hip/hip_runtime.h>
#include <math.h>

#define TT 150
#define BB 64
#define DD 2000
#define SS 3000
#define EE 100000
#define EEPAD 124160   // >= EE + SS*7 (arcs padded per-state to multiple of 8)
#define RESC 16
#define NSLOT 9
#define RESCC 0x1p-46f // exact pow2 rescale every 16 steps (growth ~7.42^16 ~= 2^46.3)

#define NT 1024        // threads per block (16 waves)
#define NBLK 256       // 1 block per CU
#define NG 32          // groups, 2 batch lanes each
#define GB 8           // blocks per group (same XCD iff bid%8 maps to XCD)
#define CAP 14336      // LDS arc slots per block (max slice ~13.9k)
#define ASTRD 3072     // dwords per alpha buffer per group (SS=3000 padded)
#define NSTMAX 2048
#define FLGSTR 32      // dwords between flags (128 B)
#define NEXB 32

// dynamic LDS layout (bytes). Alpha table at byte 0 so the gather's
// ds_read address is just (idx & 0xFFFF); ex base 12288 folds into the
// ds_read offset immediate.
#define OFF_ALPHA  0                 // SS*4 -> 12288 (packed 2xbf16 per state)
#define OFF_EX     12288             // DD*4 -> 8192  (packed 2xbf16 per pdf)
#define OFF_ARC    20480             // CAP*8 = 114688
#define OFF_RBP    135168            // (NSTMAX+1)*4 -> 8208
#define OFF_RED    143376            // 256*4 = 1024
#define OFF_SH     144400            // 16
#define DYNLDS     144416

// idx = (from<<2) | (pdf<<18): both halves are ready-made BYTE offsets into
// the packed-u32 LDS tables (from*4 <= 11996 fits 14 bits; pdf*4 <= 7996).
struct __align__(8) ArcT2 { unsigned idx; float ew; };

__device__ inline float b2f(unsigned short u) {
    union { unsigned u32; float f; } x; x.u32 = ((unsigned)u) << 16; return x.f;
}
__device__ inline unsigned short f2b(float f) {
    union { float f; unsigned u; } x; x.f = f;
    unsigned r = x.u + 0x7FFF + ((x.u >> 16) & 1);       // RNE, positive finite only
    return (unsigned short)(r >> 16);
}
__device__ inline float u2f(unsigned u) {
    union { unsigned u32; float f; } x; x.u32 = u; return x.f;
}

// ---------------- setup kernels ----------------
__global__ void k_init0(int* __restrict__ counts, unsigned* __restrict__ flags,
                        float* __restrict__ partial)
{
    int i = blockIdx.x * blockDim.x + threadIdx.x;
    if (i < SS) counts[i] = 0;
    if (i < 2 * NBLK * FLGSTR) flags[i] = 0u;
    if (i < NG * 2) partial[i] = 0.f;
}

__global__ void k_zeroarcs(ArcT2* __restrict__ arcs)
{
    int i = blockIdx.x * blockDim.x + threadIdx.x;
    if (i < EEPAD) { ArcT2 z; z.idx = 0; z.ew = 0.f; arcs[i] = z; }
}

__global__ void k_hist(const int* __restrict__ to_state, int* __restrict__ counts)
{
    int e = blockIdx.x * blockDim.x + threadIdx.x;
    if (e < EE) atomicAdd(&counts[to_state[e]], 1);
}

// prefix over counts padded to multiple of 8
__global__ void k_scan(const int* __restrict__ counts, int* __restrict__ rp,
                       int* __restrict__ cur)
{
    __shared__ int ls[1024];
    int tid = threadIdx.x;
    int s0 = tid * 3;
    int a0 = (s0 + 0 < SS) ? ((counts[s0 + 0] + 7) & ~7) : 0;
    int a1 = (s0 + 1 < SS) ? ((counts[s0 + 1] + 7) & ~7) : 0;
    int a2 = (s0 + 2 < SS) ? ((counts[s0 + 2] + 7) & ~7) : 0;
    int tsum = a0 + a1 + a2;
    ls[tid] = tsum;
    __syncthreads();
    for (int off = 1; off < 1024; off <<= 1) {
        int v = ls[tid];
        int add = (tid >= off) ? ls[tid - off] : 0;
        __syncthreads();
        ls[tid] = v + add;
        __syncthreads();
    }
    int excl = ls[tid] - tsum;
    if (s0 + 0 < SS) { rp[s0 + 0] = excl; cur[s0 + 0] = excl; }
    excl += a0;
    if (s0 + 1 < SS) { rp[s0 + 1] = excl; cur[s0 + 1] = excl; }
    excl += a1;
    if (s0 + 2 < SS) { rp[s0 + 2] = excl; cur[s0 + 2] = excl; }
    if (tid == 1023) rp[SS] = ls[1023];
}

// arc-balanced split into GB slices
__global__ void k_split(const int* __restrict__ rp, int* __restrict__ split)
{
    int j = threadIdx.x;
    if (j > GB) return;
    if (j == 0)  { split[0] = 0; return; }
    if (j == GB) { split[GB] = SS; return; }
    long long total = rp[SS];
    int target = (int)((total * j) / GB);
    int lo = 0, hi = SS;
    while (lo < hi) { int mid = (lo + hi) >> 1; if (rp[mid] >= target) hi = mid; else lo = mid + 1; }
    split[j] = lo;
}

__global__ void k_scatter(const int* __restrict__ from_state, const int* __restrict__ to_state,
                          const int* __restrict__ pdf_id, const float* __restrict__ trans_logw,
                          int* __restrict__ cur, ArcT2* __restrict__ arcs)
{
    int e = blockIdx.x * blockDim.x + threadIdx.x;
    if (e >= EE) return;
    int s = to_state[e];
    int pos = atomicAdd(&cur[s], 1);
    ArcT2 a;
    a.idx = ((unsigned)from_state[e] << 2) | ((unsigned)pdf_id[e] << 18);
    a.ew = __expf(trans_logw[e]);
    arcs[pos] = a;
}

// Bank-aware in-place reorder: within each state, put arcs with
// from%8 == position%8 at matching positions (gather lane `sub` then hits
// banks ≡ sub mod 8 -> ~4 lanes per 4-bank class instead of random 32->32).
// Pure permutation of a commutative sum -> correctness-neutral.
// One wave per state; states with n>64 arcs (essentially never) left as-is.
__global__ void k_sortbank(const int* __restrict__ rp, const int* __restrict__ counts,
                           ArcT2* __restrict__ arcs)
{
    int w = (blockIdx.x * blockDim.x + threadIdx.x) >> 6;
    int lane = threadIdx.x & 63;
    if (w >= SS) return;
    int n = counts[w];
    if (n < 2 || n > 64) return;
    int base = rp[w];
    bool valid = (lane < n);
    ArcT2 a;
    a.idx = 0; a.ew = 0.f;
    if (valid) a = arcs[base + lane];
    int c = valid ? (int)((a.idx >> 2) & 7) : -1;
    unsigned long long below = (1ull << lane) - 1ull;
    int ncArr[8];
    int myrank = 0;
    #pragma unroll
    for (int c8 = 0; c8 < 8; ++c8) {
        unsigned long long m = __ballot(valid && (c == c8));
        ncArr[c8] = (int)__popcll(m);
        if (c == c8) myrank = (int)__popcll(m & below);
    }
    // capacity of class cc among positions [0,n)
    int pos = -1;
    bool spill = false;
    if (valid) {
        int cap = (n > c) ? (((n - 1 - c) >> 3) + 1) : 0;
        if (myrank < cap) pos = c + (myrank << 3);
        else spill = true;
    }
    unsigned long long sm = __ballot(spill);
    if (spill) {
        int sr = (int)__popcll(sm & below);
        int accum = 0;
        #pragma unroll
        for (int c8 = 0; c8 < 8; ++c8) {
            int cap = (n > c8) ? (((n - 1 - c8) >> 3) + 1) : 0;
            int fr = cap - ncArr[c8]; if (fr < 0) fr = 0;
            if (pos < 0 && sr < accum + fr) {
                int kk = ncArr[c8] + (sr - accum);
                pos = c8 + (kk << 3);
            }
            accum += fr;
        }
    }
    if (valid) arcs[base + pos] = a;   // all lanes loaded before any store (same wave)
}

// ---------------- cooperative mega-kernel, verified XCD-local exchange ----------------
__global__ void __launch_bounds__(NT, 4) k_coop(
    const ArcT2* __restrict__ arcs, const int* __restrict__ rp,
    const int* __restrict__ split,
    const float* __restrict__ input, const float* __restrict__ init_logp,
    const float* __restrict__ final_logp,
    float* __restrict__ partial,         // [NG][2]
    unsigned* __restrict__ A_all,        // [NG][2][ASTRD] packed 2xbf16
    unsigned* __restrict__ flags,        // [2][NBLK][FLGSTR]
    unsigned* __restrict__ xcdbuf,       // [NBLK]
    float* __restrict__ out)
{
    extern __shared__ char dsm[];
    unsigned* la32  = (unsigned*)(dsm + OFF_ALPHA);  // packed 2xbf16 per state
    unsigned* lex32 = (unsigned*)(dsm + OFF_EX);     // packed 2xbf16 per pdf
    ArcT2*    larc  = (ArcT2*)(dsm + OFF_ARC);
    int*      rbp   = (int*)(dsm + OFF_RBP);
    float*    redf  = (float*)(dsm + OFF_RED);
    int*      sh    = (int*)(dsm + OFF_SH);

    int tid = threadIdx.x, bid = blockIdx.x;
    int x = bid & 7, y = (bid >> 3) & 3, j = bid >> 5;   // presumed-XCD, grp-in-XCD, member
    int g = x * 4 + y;                                   // group 0..31
    int lane = tid & 63, wave = tid >> 6;
    int oct = lane >> 3, sub = lane & 7;

    unsigned* Ag       = A_all + (size_t)g * (2 * ASTRD);
    unsigned* stepf    = flags;
    unsigned* auxf     = flags + (size_t)NBLK * FLGSTR;
    unsigned* myflag   = stepf + (size_t)(g * GB + j) * FLGSTR;
    unsigned* grpflag  = stepf + (size_t)(g * GB) * FLGSTR;
    unsigned* myflag2  = auxf + (size_t)(g * GB + j) * FLGSTR;
    unsigned* grpflag2 = auxf + (size_t)(g * GB) * FLGSTR;
    const float* inpG  = input + (size_t)(2 * g) * DD;

    int s0 = split[j], s1 = split[j + 1];
    int nst = s1 - s0;
    if (nst > NSTMAX) nst = NSTMAX;                      // safety (never expected)

    // ---- stage rp slice + arcs to LDS ----
    for (int i = tid; i <= nst; i += NT) rbp[i] = rp[s0 + i];
    __syncthreads();
    int rb0 = rbp[0];
    {
        int staged = rbp[nst] - rb0; if (staged > CAP) staged = CAP;
        for (int i = tid; i < staged; i += NT) larc[i] = arcs[rb0 + i];
    }

    // ---- publish XCC_ID (s_getreg id=20, offset=0, width=4 -> imm 6164) ----
    unsigned xcd = __builtin_amdgcn_s_getreg(6164) & 0xF;
    if (tid == 0)
        __hip_atomic_store(&xcdbuf[g * GB + j], xcd, __ATOMIC_RELAXED, __HIP_MEMORY_SCOPE_AGENT);
    __syncthreads();
    if (tid == 0)
        __hip_atomic_store(myflag2, 1u, __ATOMIC_RELAXED, __HIP_MEMORY_SCOPE_AGENT);
    // global aux barrier: wave0 polls all 256 aux flags (4 per lane)
    if (wave == 0) {
        while (true) {
            unsigned ok = 1;
            #pragma unroll
            for (int r = 0; r < 4; ++r) {
                unsigned v = __hip_atomic_load(auxf + (size_t)(lane * 4 + r) * FLGSTR,
                                               __ATOMIC_RELAXED, __HIP_MEMORY_SCOPE_AGENT);
                ok &= (v >= 1u);
            }
            if (__ballot(ok != 0) == ~0ULL) break;
            __builtin_amdgcn_s_sleep(1);
        }
    }
    __syncthreads();
    // decide protocol: fast iff my group is on ONE XCD and getreg is plausible
    {
        int* xint = (int*)redf;
        if (tid < NBLK)
            xint[tid] = (int)__hip_atomic_load(&xcdbuf[tid], __ATOMIC_RELAXED,
                                               __HIP_MEMORY_SCOPE_AGENT);
        __syncthreads();
        if (tid == 0) {
            int x0 = xint[g * GB];
            int uni = 1;
            for (int m = 1; m < GB; ++m) uni &= (xint[g * GB + m] == x0);
            int first = xint[0], distinct = 0;
            for (int i = 1; i < NBLK; ++i) distinct |= (xint[i] != first);
            sh[0] = uni && distinct;
        }
        __syncthreads();
    }
    const bool fast = (sh[0] != 0);
    __syncthreads();

    // ---- alpha0 (own slice) with protocol-matched stores ----
    for (int i = tid; i < nst; i += NT) {
        int s = s0 + i;
        unsigned short h = f2b(__expf(init_logp[s]));
        unsigned pk = (unsigned)h | ((unsigned)h << 16);
        if (fast) Ag[s] = pk;                            // plain store -> shared L2
        else __hip_atomic_store(Ag + s, pk, __ATOMIC_RELAXED, __HIP_MEMORY_SCOPE_AGENT);
    }
    __syncthreads();                                     // stores drained
    unsigned ep = 1;
    if (tid == 0) {
        if (fast) *(volatile unsigned*)myflag = ep;
        else __hip_atomic_store(myflag, ep, __ATOMIC_RELAXED, __HIP_MEMORY_SCOPE_AGENT);
    }
    {   // ex frame 0, packed bf16 (overlaps other blocks' arrival)
        for (int r = 0; r < 2; ++r) {
            int d = r * NT + tid;
            if (d < DD)
                lex32[d] = (unsigned)f2b(__expf(inpG[d])) |
                           ((unsigned)f2b(__expf(inpG[DD + d])) << 16);
        }
    }
    if (wave == 0) {
        while (true) {
            unsigned v = ep;
            if (lane < GB) {
                v = fast ? *(volatile const unsigned*)(grpflag + lane * FLGSTR)
                         : __hip_atomic_load(grpflag + lane * FLGSTR, __ATOMIC_RELAXED,
                                             __HIP_MEMORY_SCOPE_AGENT);
            }
            if (__ballot(v >= ep) == ~0ULL) break;
            __builtin_amdgcn_s_sleep(1);
        }
    }
    __syncthreads();

    float vf0 = 0.f, vf1 = 0.f;

    // ---- 150 steps ----
    for (int k = 0; k < TT; ++k) {
        const unsigned* Ap32 = Ag + (k & 1) * ASTRD;
        unsigned*       An32 = Ag + ((k + 1) & 1) * ASTRD;
        bool last = (k == TT - 1);
        bool resc = (((k + 1) & (RESC - 1)) == 0);

        // phase A: alpha_k (12 KB packed bf16) -> LDS, straight u64 copy
        if (fast) {
            for (int idx = tid; idx < SS / 2; idx += NT) {
                unsigned long long v =
                    *(volatile const unsigned long long*)((const unsigned long long*)Ap32 + idx);
                ((unsigned long long*)la32)[idx] = v;
            }
        } else {
            for (int idx = tid; idx < SS / 2; idx += NT) {
                unsigned long long v = __hip_atomic_load(
                    (const unsigned long long*)Ap32 + idx, __ATOMIC_RELAXED,
                    __HIP_MEMORY_SCOPE_AGENT);
                ((unsigned long long*)la32)[idx] = v;
            }
        }
        __syncthreads();

        // phase B: gather own states (8 lanes per state, 8 states per wave)
        for (int base = wave * 8; base < nst; base += 128) {
            int li = base + oct;
            bool has = (li < nst);
            float acc0 = 0.f, acc1 = 0.f;
            int sg = 0;
            if (has) {
                sg = s0 + li;
                int ra = rbp[li], re = rbp[li + 1];
                int nit = (re - ra) >> 3;
                if (re - rb0 <= CAP) {
                    int bix = ra - rb0 + sub;
                    for (int t = 0; t < nit; ++t) {
                        ArcT2 a = larc[bix + t * 8];
                        unsigned au = *(const unsigned*)(dsm + (a.idx & 0xFFFFu));
                        unsigned eu = *(const unsigned*)(dsm + OFF_EX + (a.idx >> 16));
                        acc0 = fmaf(u2f(au << 16), a.ew * u2f(eu << 16), acc0);
                        acc1 = fmaf(u2f(au & 0xFFFF0000u), a.ew * u2f(eu & 0xFFFF0000u), acc1);
                    }
                } else {
                    for (int t = 0; t < nit; ++t) {      // safety overflow path
                        ArcT2 a = arcs[ra + t * 8 + sub];
                        unsigned au = *(const unsigned*)(dsm + (a.idx & 0xFFFFu));
                        unsigned eu = *(const unsigned*)(dsm + OFF_EX + (a.idx >> 16));
                        acc0 = fmaf(u2f(au << 16), a.ew * u2f(eu << 16), acc0);
                        acc1 = fmaf(u2f(au & 0xFFFF0000u), a.ew * u2f(eu & 0xFFFF0000u), acc1);
                    }
                }
            }
            acc0 += __shfl_xor(acc0, 1, 64); acc1 += __shfl_xor(acc1, 1, 64);
            acc0 += __shfl_xor(acc0, 2, 64); acc1 += __shfl_xor(acc1, 2, 64);
            acc0 += __shfl_xor(acc0, 4, 64); acc1 += __shfl_xor(acc1, 4, 64);
            if (has && sub == 0) {
                if (resc) { acc0 *= RESCC; acc1 *= RESCC; }
                if (last) {
                    float ef = __expf(final_logp[sg]);
                    vf0 = fmaf(acc0, ef, vf0);
                    vf1 = fmaf(acc1, ef, vf1);
                } else {
                    unsigned pk = (unsigned)f2b(acc0) | ((unsigned)f2b(acc1) << 16);
                    if (fast) An32[sg] = pk;             // plain store -> shared L2
                    else __hip_atomic_store(An32 + sg, pk, __ATOMIC_RELAXED,
                                            __HIP_MEMORY_SCOPE_AGENT);
                }
            }
        }
        if (last) break;
        __syncthreads();                                 // stores drained (vmcnt 0)
        ++ep;
        if (tid == 0) {
            if (fast) *(volatile unsigned*)myflag = ep;
            else __hip_atomic_store(myflag, ep, __ATOMIC_RELAXED, __HIP_MEMORY_SCOPE_AGENT);
        }
        {   // ex_{k+1} (independent of alpha) — overlaps others' arrival
            const float* fr = inpG + (size_t)(k + 1) * BB * DD;
            for (int r = 0; r < 2; ++r) {
                int d = r * NT + tid;
                if (d < DD)
                    lex32[d] = (unsigned)f2b(__expf(fr[d])) |
                               ((unsigned)f2b(__expf(fr[DD + d])) << 16);
            }
        }
        if (wave == 0) {
            while (true) {
                unsigned v = ep;
                if (lane < GB) {
                    v = fast ? *(volatile const unsigned*)(grpflag + lane * FLGSTR)
                             : __hip_atomic_load(grpflag + lane * FLGSTR, __ATOMIC_RELAXED,
                                                 __HIP_MEMORY_SCOPE_AGENT);
                }
                if (__ballot(v >= ep) == ~0ULL) break;
                __builtin_amdgcn_s_sleep(1);
            }
        }
        __syncthreads();
    }

    // ---- epilogue: reduce objf over this block's states ----
    if (sub == 0) {
        redf[(wave * 8 + oct) * 2 + 0] = vf0;
        redf[(wave * 8 + oct) * 2 + 1] = vf1;
    }
    __syncthreads();
    if (tid < 2) {
        float S = 0.f;
        for (int i = 0; i < 128; ++i) S += redf[i * 2 + tid];
        __hip_atomic_fetch_add(&partial[g * 2 + tid], S, __ATOMIC_RELAXED,
                               __HIP_MEMORY_SCOPE_AGENT);
    }
    __syncthreads();
    if (tid == 0)
        __hip_atomic_store(myflag2, 2u, __ATOMIC_RELAXED, __HIP_MEMORY_SCOPE_AGENT);
    if (j == 0) {
        if (wave == 0) {
            while (true) {
                unsigned v = 2;
                if (lane < GB)
                    v = __hip_atomic_load(grpflag2 + lane * FLGSTR, __ATOMIC_RELAXED,
                                          __HIP_MEMORY_SCOPE_AGENT);
                if (__ballot(v >= 2) == ~0ULL) break;
                __builtin_amdgcn_s_sleep(1);
            }
        }
        __syncthreads();
        if (tid < 2) {
            float S = __hip_atomic_load(&partial[g * 2 + tid], __ATOMIC_RELAXED,
                                        __HIP_MEMORY_SCOPE_AGENT);
            float lg = logf(S) + (float)(NSLOT * 46) * 0.69314718055994531f;
            atomicAdd(out, lg);
        }
    }
}

// ---------------- fallback path (round-6 per-step kernels) ----------------
template <int THREADS>
__device__ inline void transpose_exp_t(const float* __restrict__ frame,
                                       unsigned short* __restrict__ dst,
                                       int tile_id, int tid, unsigned short* smem)
{
    int d0 = tile_id * 64;
    #pragma unroll
    for (int it = 0; it < 4096 / THREADS; ++it) {
        int idx = it * THREADS + tid;
        int dl = idx & 63, bl = idx >> 6;
        int d = d0 + dl;
        float v = 0.f;
        if (d < DD) v = __expf(frame[bl * DD + d]);
        smem[dl * 65 + bl] = f2b(v);
    }
    __syncthreads();
    #pragma unroll
    for (int it = 0; it < 4096 / THREADS; ++it) {
        int idx = it * THREADS + tid;
        int bo = idx & 63, dq = idx >> 6;
        int d = d0 + dq;
        if (d < DD) dst[(d << 6) + bo] = smem[dq * 65 + bo];
    }
    __syncthreads();
}

__global__ void k_initA(const float* __restrict__ init_logp,
                        unsigned short* __restrict__ A0, float* __restrict__ M2)
{
    int idx = blockIdx.x * blockDim.x + threadIdx.x;
    if (idx < SS * BB) A0[idx] = f2b(__expf(init_logp[idx >> 6]));
    if (idx < NSLOT * 16 * 64) M2[idx] = 0.f;
}

__global__ void k_transpose0(const float* __restrict__ frame, unsigned short* __restrict__ dst)
{
    __shared__ unsigned short tile[64 * 65];
    transpose_exp_t<256>(frame, dst, blockIdx.x, threadIdx.x, tile);
}

__global__ void __launch_bounds__(256) k_step(
    const ArcT2* __restrict__ arcs, const int* __restrict__ rp,
    const unsigned short* __restrict__ Ap, unsigned short* __restrict__ An,
    const unsigned short* __restrict__ ec,
    const float* __restrict__ frameNext, unsigned short* __restrict__ en,
    float* __restrict__ M2, int maxSlot, int useSlot)
{
    __shared__ unsigned short tile[64 * 65];
    __shared__ float part[256];
    __shared__ float rcpA[64];
    int tid = threadIdx.x, bid = blockIdx.x;
    if (bid >= SS) { transpose_exp_t<256>(frameNext, en, bid - SS, tid, tile); return; }
    int lane = tid & 63, wave = tid >> 6;
    if (useSlot >= 0 && wave == 0) {
        const float* Mrow = M2 + useSlot * (16 * 64);
        float m = Mrow[lane];
        #pragma unroll
        for (int g = 1; g < 16; ++g) m = fmaxf(m, Mrow[g * 64 + lane]);
        rcpA[lane] = 1.0f / m;
    }
    int rbeg = rp[bid], rend = rp[bid + 1];
    float acc = 0.f;
    for (int i = rbeg + wave; i < rend; i += 4) {
        ArcT2 a = arcs[i];
        int from = (a.idx & 0xFFFF) >> 2, pdf = a.idx >> 18;
        acc = fmaf(b2f(Ap[(from << 6) + lane]), a.ew * b2f(ec[(pdf << 6) + lane]), acc);
    }
    part[tid] = acc;
    __syncthreads();
    if (wave == 0) {
        float sum = part[lane] + part[64 + lane] + part[128 + lane] + part[192 + lane];
        if (useSlot >= 0) sum *= rcpA[lane];
        An[(bid << 6) + lane] = f2b(sum);
        if (maxSlot >= 0)
            atomicMax((unsigned*)&M2[maxSlot * (16 * 64) + (bid & 15) * 64 + lane],
                      __float_as_uint(sum));
    }
}

__global__ void k_fin(const unsigned short* __restrict__ AT, const float* __restrict__ final_logp,
                      const float* __restrict__ M2, float* __restrict__ out)
{
    __shared__ float red[1024];
    int tid = threadIdx.x;
    int lane = tid & 63, chunk = tid >> 6;
    float psum = 0.f;
    for (int s = chunk; s < SS; s += 16)
        psum += b2f(AT[(s << 6) + lane]) * __expf(final_logp[s]);
    red[tid] = psum;
    __syncthreads();
    if (tid < 64) {
        float sum = 0.f;
        #pragma unroll
        for (int c = 0; c < 16; ++c) sum += red[c * 64 + tid];
        float lg = logf(sum);
        #pragma unroll
        for (int r = 0; r < NSLOT; ++r) {
            const float* Mrow = M2 + r * (16 * 64);
            float m = Mrow[tid];
            #pragma unroll
            for (int g = 1; g < 16; ++g) m = fmaxf(m, Mrow[g * 64 + tid]);
            lg += logf(m);
        }
        #pragma unroll
        for (int off = 32; off > 0; off >>= 1) lg += __shfl_down(lg, off);
        if (tid == 0) out[0] = lg;
    }
}

extern "C" void kernel_launch(void* const* d_in, const int* in_sizes, int n_in,
                              void* d_out, int out_size, void* d_ws, size_t ws_size,
                              hipStream_t stream)
{
    const float* input      = (const float*)d_in[0];
    const float* trans_logw = (const float*)d_in[1];
    const float* init_logp  = (const float*)d_in[2];
    const float* final_logp = (const float*)d_in[3];
    const int*   from_state = (const int*)d_in[4];
    const int*   to_state   = (const int*)d_in[5];
    const int*   pdf_id     = (const int*)d_in[6];
    float* out = (float*)d_out;

    char* ws = (char*)d_ws;
    size_t off = 0;
    auto alloc = [&](size_t bytes) -> char* {
        char* p = ws + off;
        off = (off + bytes + 255) & ~(size_t)255;
        return p;
    };
    ArcT2* arcs  = (ArcT2*)alloc((size_t)EEPAD * sizeof(ArcT2));
    int* rp      = (int*)alloc((size_t)(SS + 1) * 4);
    int* cur     = (int*)alloc((size_t)SS * 4);
    int* counts  = (int*)alloc((size_t)SS * 4);
    int* split   = (int*)alloc((size_t)(GB + 1) * 4);
    unsigned* A_all = (unsigned*)alloc((size_t)NG * 2 * ASTRD * 4);
    float* partial  = (float*)alloc((size_t)NG * 2 * 4);
    unsigned* flags = (unsigned*)alloc((size_t)2 * NBLK * FLGSTR * 4);
    unsigned* xcdbuf = (unsigned*)alloc((size_t)NBLK * 4);
    // fallback buffers
    unsigned short* A0  = (unsigned short*)alloc((size_t)SS * BB * 2);
    unsigned short* A1  = (unsigned short*)alloc((size_t)SS * BB * 2);
    unsigned short* EX0 = (unsigned short*)alloc((size_t)DD * BB * 2);
    unsigned short* EX1 = (unsigned short*)alloc((size_t)DD * BB * 2);
    float* M2    = (float*)alloc((size_t)NSLOT * 16 * 64 * 4);
    (void)ws_size; (void)in_sizes; (void)n_in; (void)out_size;

    k_init0<<<64, 256, 0, stream>>>(counts, flags, partial);
    k_zeroarcs<<<(EEPAD + 255) / 256, 256, 0, stream>>>(arcs);
    k_hist<<<(EE + 255) / 256, 256, 0, stream>>>(to_state, counts);
    k_scan<<<1, 1024, 0, stream>>>(counts, rp, cur);
    k_split<<<1, 16, 0, stream>>>(rp, split);
    k_scatter<<<(EE + 255) / 256, 256, 0, stream>>>(from_state, to_state, pdf_id,
                                                    trans_logw, cur, arcs);
    k_sortbank<<<(SS * 64 + 255) / 256, 256, 0, stream>>>(rp, counts, arcs);
    hipMemsetAsync(d_out, 0, sizeof(float), stream);

    hipFuncSetAttribute((const void*)k_coop, hipFuncAttributeMaxDynamicSharedMemorySize,
                        DYNLDS);
    int nb = 0;
    hipOccupancyMaxActiveBlocksPerMultiprocessor(&nb, (const void*)k_coop, NT, DYNLDS);
    if (nb >= 1) {
        void* kp[11] = {
            (void*)&arcs, (void*)&rp, (void*)&split, (void*)&input, (void*)&init_logp,
            (void*)&final_logp, (void*)&partial, (void*)&A_all, (void*)&flags,
            (void*)&xcdbuf, (void*)&out
        };
        hipError_t e = hipLaunchCooperativeKernel((const void*)k_coop, dim3(NBLK), dim3(NT),
                                                  kp, DYNLDS, stream);
        if (e == hipSuccess) return;
    }

    // Fallback: per-step kernels (bf16 state), known-passing structure.
    k_initA<<<(SS * BB + 255) / 256, 256, 0, stream>>>(init_logp, A0, M2);
    k_transpose0<<<NEXB, 256, 0, stream>>>(input, EX0);
    unsigned short* A[2]  = {A0, A1};
    unsigned short* EX[2] = {EX0, EX1};
    for (int k = 0; k < TT; ++k) {
        int kn = k + 1;
        int useSlot = (k > 0 && (k % RESC) == 0) ? (k / RESC - 1) : -1;
        int maxSlot = (kn < TT && (kn % RESC) == 0) ? (kn / RESC - 1) : -1;
        int grid = SS + ((kn < TT) ? NEXB : 0);
        const float* fnext = (kn < TT) ? (input + (size_t)kn * BB * DD) : nullptr;
        k_step<<<grid, 256, 0, stream>>>(arcs, rp, A[k & 1], A[kn & 1], EX[k & 1],
                                         fnext, EX[kn & 1], M2, maxSlot, useSlot);
    }
    k_fin<<<1, 1024, 0, stream>>>(A[TT & 1], final_logp, M2, out);
}